// Round 8
// baseline (174.389 us; speedup 1.0000x reference)
//
#include <hip/hip_runtime.h>
#include <math.h>

#define NV 6890
#define N3 20670       // NV*3
#define NJNT 24
#define NBETA 10
#define NPF 207
#define NJO 19
#define NBATCH 512
#define NJK 456        // NJO*NJNT
#define NJKP 512       // padded jk (GEMM N)
#define NCOEF 218      // [pf 207 | beta 10 | 1]
#define PROWSP 704     // padded P rows (GEMM M)
#define KPAD 6912      // 12 * 576
#define KSPLIT 12
#define KCH 576        // 9 * 64
#define CSTR 224       // pfc row stride

// kA role boundaries
#define TRB 646        // ceil(NV*NJNT/256)
#define SJB 264        // 24*11
// kPrep role boundaries
#define CMB 512
#define PMB 219        // 207 pdirs + 10 sdirs + 1 (vtmpl+ones)
#define PZB 49         // pad rows 655..703

typedef __attribute__((ext_vector_type(8))) short bfx8;
typedef __attribute__((ext_vector_type(4))) float fx4;

__device__ inline short f2bf(float f) {
  union { float f; unsigned u; } x; x.f = f;
  unsigned r = (x.u + 0x7fffu + ((x.u >> 16) & 1u)) >> 16;
  return (short)r;
}

// ============ kA: transpose || SJ || rodrigues (all parallel-short roles) ============
__global__ void __launch_bounds__(256) kA(const float* __restrict__ jr,
                                          const float* __restrict__ lbs,
                                          const float* __restrict__ Jreg,
                                          const float* __restrict__ sdirs,
                                          const float* __restrict__ vtmpl,
                                          const float* __restrict__ theta,
                                          const float* __restrict__ beta,
                                          float* __restrict__ jrT, float* __restrict__ wT,
                                          float* __restrict__ SJ, float* __restrict__ Rs,
                                          float* __restrict__ pfc) {
  __shared__ float red[4][3];
  int bx = blockIdx.x, tid = threadIdx.x;
  if (bx < TRB) {
    int idx = bx * 256 + tid;
    if (idx < NV * NJO)  { int v = idx / NJO,  j = idx - v * NJO;  jrT[j * NV + v] = jr[idx]; }
    if (idx < NV * NJNT) { int v = idx / NJNT, k = idx - v * NJNT; wT[k * NV + v]  = lbs[idx]; }
  } else if (bx < TRB + SJB) {
    int s = bx - TRB;
    int j = s % NJNT, k = s / NJNT;
    const float* src = (k < NBETA) ? (sdirs + (size_t)k * N3) : vtmpl;
    float a0 = 0.f, a1 = 0.f, a2 = 0.f;
    for (int v = tid; v < NV; v += 256) {
      float w = Jreg[v * NJNT + j];
      a0 += w * src[v * 3 + 0];
      a1 += w * src[v * 3 + 1];
      a2 += w * src[v * 3 + 2];
    }
    int lane = tid & 63, wid = tid >> 6;
#pragma unroll
    for (int s2 = 1; s2 < 64; s2 <<= 1) {
      a0 += __shfl_xor(a0, s2); a1 += __shfl_xor(a1, s2); a2 += __shfl_xor(a2, s2);
    }
    if (lane == 0) { red[wid][0] = a0; red[wid][1] = a1; red[wid][2] = a2; }
    __syncthreads();
    if (tid == 0) {
      float* o = SJ + (k * NJNT + j) * 3;
      o[0] = red[0][0] + red[1][0] + red[2][0] + red[3][0];
      o[1] = red[0][1] + red[1][1] + red[2][1] + red[3][1];
      o[2] = red[0][2] + red[1][2] + red[2][2] + red[3][2];
    }
  } else {
    int b = (bx - TRB - SJB) * 256 + tid;
    if (b >= NBATCH) return;
    for (int j = 0; j < NJNT; ++j) {
      float a0 = theta[b * 72 + j * 3 + 0];
      float a1 = theta[b * 72 + j * 3 + 1];
      float a2 = theta[b * 72 + j * 3 + 2];
      float e0 = a0 + 1e-8f, e1 = a1 + 1e-8f, e2 = a2 + 1e-8f;
      float ang = sqrtf(e0 * e0 + e1 * e1 + e2 * e2);
      float inv = 1.0f / ang;
      float h = 0.5f * ang;
      float w = cosf(h), s = sinf(h);
      float x = a0 * inv * s, y = a1 * inv * s, z = a2 * inv * s;
      float R[9];
      R[0] = w*w + x*x - y*y - z*z; R[1] = 2.f*(x*y - w*z); R[2] = 2.f*(x*z + w*y);
      R[3] = 2.f*(x*y + w*z); R[4] = w*w - x*x + y*y - z*z; R[5] = 2.f*(y*z - w*x);
      R[6] = 2.f*(x*z - w*y); R[7] = 2.f*(y*z + w*x); R[8] = w*w - x*x - y*y + z*z;
#pragma unroll
      for (int r = 0; r < 9; ++r) Rs[b * 216 + j * 9 + r] = R[r];
      if (j >= 1) {
#pragma unroll
        for (int r = 0; r < 9; ++r)
          pfc[b * CSTR + (j - 1) * 9 + r] = R[r] - ((r % 4 == 0) ? 1.0f : 0.0f);
      }
    }
#pragma unroll
    for (int i = 0; i < NBETA; ++i) pfc[b * CSTR + NPF + i] = beta[b * NBETA + i];
    pfc[b * CSTR + NPF + NBETA] = 1.0f;
  }
}

// ============ k_chain2: fused J + kinematic chain, all-static indexing ============
// J[b][r] = SJ[10][r] + sum_k beta[b,k]*SJ[k][r]  (J kept in registers, static idx)
// world A -> Aw (global, parent reads); A gets rotation + RELATIVE col3 inline.
__global__ void k_chain2(const float* __restrict__ beta, const float* __restrict__ SJ,
                         const float* __restrict__ Rs,
                         float* __restrict__ Aw, float* __restrict__ A) {
  constexpr int par[NJNT] = {0,0,0,0,1,2,3,4,5,6,7,8,9,9,9,12,13,14,16,17,18,19,20,21};
  int b = blockIdx.x * 64 + threadIdx.x;
  if (b >= NBATCH) return;
  float bb[NBETA];
#pragma unroll
  for (int k = 0; k < NBETA; ++k) bb[k] = beta[b * NBETA + k];
  float J[72];
#pragma unroll
  for (int r = 0; r < 72; ++r) {
    float a = SJ[NBETA * 72 + r];
#pragma unroll
    for (int k = 0; k < NBETA; ++k) a += bb[k] * SJ[k * 72 + r];
    J[r] = a;
  }
  const float* Rb = Rs + b * 216;
  float* Awb = Aw + b * 288;
  float* Ab  = A  + b * 288;
  // joint 0
#pragma unroll
  for (int r = 0; r < 3; ++r) {
    float r0 = Rb[r * 3 + 0], r1 = Rb[r * 3 + 1], r2 = Rb[r * 3 + 2];
    Awb[r * 4 + 0] = r0; Awb[r * 4 + 1] = r1; Awb[r * 4 + 2] = r2;
    Awb[r * 4 + 3] = J[r];
    Ab[r * 4 + 0] = r0; Ab[r * 4 + 1] = r1; Ab[r * 4 + 2] = r2;
    Ab[r * 4 + 3] = J[r] - (r0 * J[0] + r1 * J[1] + r2 * J[2]);
  }
#pragma unroll
  for (int i = 1; i < NJNT; ++i) {
    constexpr int pi[NJNT] = {0,0,0,0,1,2,3,4,5,6,7,8,9,9,9,12,13,14,16,17,18,19,20,21};
    const int p = pi[i];
    const float* P = Awb + p * 12;
    const float* R = Rb + i * 9;
    float t0 = J[i * 3 + 0] - J[p * 3 + 0];
    float t1 = J[i * 3 + 1] - J[p * 3 + 1];
    float t2 = J[i * 3 + 2] - J[p * 3 + 2];
    float jx = J[i * 3 + 0], jy = J[i * 3 + 1], jz = J[i * 3 + 2];
#pragma unroll
    for (int r = 0; r < 3; ++r) {
      float p0 = P[r * 4 + 0], p1 = P[r * 4 + 1], p2 = P[r * 4 + 2], p3 = P[r * 4 + 3];
      float o0 = p0 * R[0] + p1 * R[3] + p2 * R[6];
      float o1 = p0 * R[1] + p1 * R[4] + p2 * R[7];
      float o2 = p0 * R[2] + p1 * R[5] + p2 * R[8];
      float o3 = p0 * t0 + p1 * t1 + p2 * t2 + p3;
      Awb[i * 12 + r * 4 + 0] = o0;
      Awb[i * 12 + r * 4 + 1] = o1;
      Awb[i * 12 + r * 4 + 2] = o2;
      Awb[i * 12 + r * 4 + 3] = o3;
      Ab[i * 12 + r * 4 + 0] = o0;
      Ab[i * 12 + r * 4 + 1] = o1;
      Ab[i * 12 + r * 4 + 2] = o2;
      Ab[i * 12 + r * 4 + 3] = o3 - (o0 * jx + o1 * jy + o2 * jz);
    }
    (void)par;
  }
}

// ============ kPrep: Cm || Pm (coalesced) || pad-zero — uniform streaming only ========
__global__ void __launch_bounds__(256) kPrep(const float* __restrict__ jrT,
                                             const float* __restrict__ wT,
                                             const float* __restrict__ pdirs,
                                             const float* __restrict__ sdirs,
                                             const float* __restrict__ vtmpl,
                                             short* __restrict__ Cb, short* __restrict__ Pb) {
  __shared__ float buf[768];
  int bx = blockIdx.x, tid = threadIdx.x;
  if (bx < CMB) {
    int jk = bx;
    bool real = (jk < NJK);
    int j = jk / NJNT, k = jk - j * NJNT;
    for (int g = tid; g < KPAD; g += 256) {
      float val = (real && g < NV) ? jrT[j * NV + g] * wT[k * NV + g] : 0.f;
      Cb[(size_t)jk * KPAD + g] = f2bf(val);
    }
  } else if (bx < CMB + PMB) {
    int s = bx - CMB;
    const float* src; int base;
    if (s < 207)      { src = pdirs + (size_t)s * N3;         base = 3 * s; }
    else if (s < 217) { src = sdirs + (size_t)(s - 207) * N3; base = 621 + 3 * (s - 207); }
    else              { src = vtmpl;                           base = 651; }
    for (int g = 0; g < 27; ++g) {
      int f0 = g * 768;
#pragma unroll
      for (int c = 0; c < 3; ++c) {
        int fi = f0 + c * 256 + tid;
        buf[c * 256 + tid] = (fi < N3) ? src[fi] : 0.f;
      }
      __syncthreads();
      int v0 = g * 256;
#pragma unroll
      for (int q = 0; q < 3; ++q)
        Pb[(size_t)(base + q) * KPAD + v0 + tid] = f2bf(buf[tid * 3 + q]);
      __syncthreads();
    }
    if (s == 217) {
      for (int i = tid; i < KPAD; i += 256)
        Pb[(size_t)654 * KPAD + i] = (i < NV) ? f2bf(1.0f) : (short)0;
    }
  } else {
    int row = 655 + (bx - CMB - PMB);
    for (int g = tid; g < KPAD; g += 256)
      Pb[(size_t)row * KPAD + g] = (short)0;
  }
}

// ============ MFMA GEMM: Dpart[z][m][n] = sum_k P[m][k]*C[n][k] ============
__global__ void __launch_bounds__(256) k_gemm(const short* __restrict__ Pb,
                                              const short* __restrict__ Cb,
                                              float* __restrict__ Dpart) {
  int m0 = blockIdx.x * 64;
  int n0 = blockIdx.y * 64;
  int kb0 = blockIdx.z * KCH;
  __shared__ __align__(16) short As[64 * 64];
  __shared__ __align__(16) short Bs[64 * 64];
  int t = threadIdx.x;
  int wid = t >> 6, lane = t & 63;
  int frow = wid * 16 + (lane & 15);
  int fgrp = lane >> 4;
  fx4 acc[4];
#pragma unroll
  for (int j = 0; j < 4; ++j)
#pragma unroll
    for (int r = 0; r < 4; ++r) acc[j][r] = 0.f;

  int c0 = t, c1 = t + 256;
  int row0 = c0 >> 3, g0 = c0 & 7, sw0 = g0 ^ (row0 & 7);
  int row1 = c1 >> 3, g1 = c1 & 7, sw1 = g1 ^ (row1 & 7);

  for (int kk = 0; kk < KCH / 64; ++kk) {
    int kb = kb0 + kk * 64;
    *(bfx8*)(As + row0 * 64 + sw0 * 8) = *(const bfx8*)(Pb + (size_t)(m0 + row0) * KPAD + kb + g0 * 8);
    *(bfx8*)(As + row1 * 64 + sw1 * 8) = *(const bfx8*)(Pb + (size_t)(m0 + row1) * KPAD + kb + g1 * 8);
    *(bfx8*)(Bs + row0 * 64 + sw0 * 8) = *(const bfx8*)(Cb + (size_t)(n0 + row0) * KPAD + kb + g0 * 8);
    *(bfx8*)(Bs + row1 * 64 + sw1 * 8) = *(const bfx8*)(Cb + (size_t)(n0 + row1) * KPAD + kb + g1 * 8);
    __syncthreads();
#pragma unroll
    for (int ks = 0; ks < 2; ++ks) {
      int ga = ks * 4 + fgrp;
      bfx8 a = *(const bfx8*)(As + frow * 64 + (ga ^ (frow & 7)) * 8);
#pragma unroll
      for (int j = 0; j < 4; ++j) {
        int bcol = j * 16 + (lane & 15);
        bfx8 b = *(const bfx8*)(Bs + bcol * 64 + (ga ^ (bcol & 7)) * 8);
        acc[j] = __builtin_amdgcn_mfma_f32_16x16x32_bf16(a, b, acc[j], 0, 0, 0);
      }
    }
    __syncthreads();
  }
  float* dst = Dpart + (size_t)blockIdx.z * PROWSP * NJKP
             + (size_t)(m0 + wid * 16 + (lane >> 4) * 4) * NJKP + n0 + (lane & 15);
#pragma unroll
  for (int j = 0; j < 4; ++j)
#pragma unroll
    for (int r = 0; r < 4; ++r)
      dst[(size_t)r * NJKP + j * 16] = acc[j][r];
}

// ============ reduce K-split partials (float4) ============
__global__ void k_redD(const float* __restrict__ Dpart, float* __restrict__ D) {
  int i = blockIdx.x * 256 + threadIdx.x;
  if (i >= PROWSP * NJKP / 4) return;
  const float4* dp = (const float4*)Dpart;
  float4 s = dp[i];
#pragma unroll
  for (int z = 1; z < KSPLIT; ++z) {
    float4 v = dp[(size_t)z * (PROWSP * NJKP / 4) + i];
    s.x += v.x; s.y += v.y; s.z += v.z; s.w += v.w;
  }
  ((float4*)D)[i] = s;
}

// ============ k_S3: S[b][jk][q] = sum_r pfc[b][r]*D[3r+q][jk] ============
// grid (8 jk-tiles, 64 b-tiles of 8). 256 thr = 64 jk-lanes x 4 waves x 2 b.
__global__ void __launch_bounds__(256) k_S3(const float* __restrict__ D,
                                            const float* __restrict__ pfc,
                                            float* __restrict__ S) {
  int n0 = blockIdx.x * 64;
  int b0 = blockIdx.y * 8;
  int tid = threadIdx.x;
  __shared__ float cf[8][NCOEF + 2];
  for (int i = tid; i < 8 * NCOEF; i += 256) {
    int b = i / NCOEF, r = i - b * NCOEF;
    cf[b][r] = pfc[(b0 + b) * CSTR + r];
  }
  __syncthreads();
  int jk = n0 + (tid & 63);
  int bg = (tid >> 6) * 2;
  float a00=0.f,a01=0.f,a02=0.f,a10=0.f,a11=0.f,a12=0.f;
  const float* Dp = D + jk;
#pragma unroll 4
  for (int r = 0; r < NCOEF; ++r) {
    float d0 = Dp[(size_t)(3 * r + 0) * NJKP];
    float d1 = Dp[(size_t)(3 * r + 1) * NJKP];
    float d2 = Dp[(size_t)(3 * r + 2) * NJKP];
    float c0 = cf[bg + 0][r];
    float c1 = cf[bg + 1][r];
    a00 += c0 * d0; a01 += c0 * d1; a02 += c0 * d2;
    a10 += c1 * d0; a11 += c1 * d1; a12 += c1 * d2;
  }
  if (jk < NJK) {
    float* o0 = S + ((size_t)(b0 + bg + 0) * NJK + jk) * 3;
    float* o1 = S + ((size_t)(b0 + bg + 1) * NJK + jk) * 3;
    o0[0] = a00; o0[1] = a01; o0[2] = a02;
    o1[0] = a10; o1[1] = a11; o1[2] = a12;
  }
}

// ============ final: joints[b,j,c] = sum_k A[b,k,c,:].[S, c0] ============
__global__ void k_final(const float* __restrict__ S, const float* __restrict__ D,
                        const float* __restrict__ A, float* __restrict__ out) {
  int idx = blockIdx.x * 256 + threadIdx.x;
  if (idx >= NBATCH * NJO * 3) return;
  int b = idx / 57, r = idx - b * 57;
  int j = r / 3, c = r - j * 3;
  const float* c0 = D + (size_t)654 * NJKP + j * NJNT;
  float acc = 0.f;
#pragma unroll
  for (int k = 0; k < NJNT; ++k) {
    const float* Ar = A + b * 288 + k * 12 + c * 4;
    const float* Sr = S + ((size_t)b * NJK + j * NJNT + k) * 3;
    acc += Ar[0] * Sr[0] + Ar[1] * Sr[1] + Ar[2] * Sr[2] + Ar[3] * c0[k];
  }
  out[idx] = acc;
}

extern "C" void kernel_launch(void* const* d_in, const int* in_sizes, int n_in,
                              void* d_out, int out_size, void* d_ws, size_t ws_size,
                              hipStream_t stream) {
  const float* beta  = (const float*)d_in[0];
  const float* theta = (const float*)d_in[1];
  const float* vtmpl = (const float*)d_in[2];
  const float* sdirs = (const float*)d_in[3];
  const float* Jreg  = (const float*)d_in[4];
  const float* pdirs = (const float*)d_in[5];
  const float* lbs   = (const float*)d_in[6];
  const float* jreg2 = (const float*)d_in[7];
  float* out = (float*)d_out;

  float* ws    = (float*)d_ws;
  short* Cb    = (short*)ws;                              // 512*6912 bf16
  short* Pb    = Cb + (size_t)NJKP * KPAD;                // 704*6912 bf16
  float* Dpart = (float*)(Pb + (size_t)PROWSP * KPAD);    // 12*704*512 f32
  float* D     = Dpart + (size_t)KSPLIT * PROWSP * NJKP;  // 704*512
  float* S     = D     + (size_t)PROWSP * NJKP;           // 512*456*3
  float* pfc   = S     + (size_t)NBATCH * NJK * 3;        // 512*224
  float* Rs    = pfc   + (size_t)NBATCH * CSTR;           // 512*216
  float* Aw    = Rs    + (size_t)NBATCH * 216;            // 512*288
  float* A     = Aw    + (size_t)NBATCH * 288;            // 512*288
  float* jrT   = A     + (size_t)NBATCH * 288;            // 19*6890
  float* wT    = jrT   + (size_t)NJO * NV;                // 24*6890
  float* SJ    = wT    + (size_t)NJNT * NV;               // 11*72

  kA<<<dim3(TRB + SJB + 2), 256, 0, stream>>>(jreg2, lbs, Jreg, sdirs, vtmpl, theta, beta,
                                              jrT, wT, SJ, Rs, pfc);
  k_chain2<<<dim3(8), 64, 0, stream>>>(beta, SJ, Rs, Aw, A);
  kPrep<<<dim3(CMB + PMB + PZB), 256, 0, stream>>>(jrT, wT, pdirs, sdirs, vtmpl, Cb, Pb);
  k_gemm<<<dim3(PROWSP / 64, NJKP / 64, KSPLIT), 256, 0, stream>>>(Pb, Cb, Dpart);
  k_redD<<<dim3(PROWSP * NJKP / 4 / 256), 256, 0, stream>>>(Dpart, D);
  k_S3<<<dim3(NJKP / 64, NBATCH / 8), 256, 0, stream>>>(D, pfc, S);
  k_final<<<dim3((NBATCH * NJO * 3 + 255) / 256), 256, 0, stream>>>(S, D, A, out);
}

// Round 9
// 152.752 us; speedup vs baseline: 1.1416x; 1.1416x over previous
//
#include <hip/hip_runtime.h>
#include <math.h>

#define NV 6890
#define N3 20670       // NV*3
#define NJNT 24
#define NBETA 10
#define NPF 207
#define NJO 19
#define NBATCH 512
#define NJK 456        // NJO*NJNT
#define NJKP 512       // padded jk (GEMM N)
#define NCOEF 218      // [pf 207 | beta 10 | 1]
#define PROWSP 704     // padded P rows (GEMM M)
#define KPAD 6912      // 12 * 576
#define KSPLIT 12
#define KCH 576        // 9 * 64
#define CSTR 224       // pfc row stride

// kA role boundaries
#define TRB 646        // ceil(NV*NJNT/256)
#define SJB 264        // 24*11
// kPrep role boundaries
#define CMB 512
#define PMB 219        // 207 pdirs + 10 sdirs + 1 (vtmpl+ones)
#define PZB 49         // pad rows 655..703

typedef __attribute__((ext_vector_type(8))) short bfx8;
typedef __attribute__((ext_vector_type(4))) float fx4;

__constant__ int d_par[NJNT] = {0,0,0,0,1,2,3,4,5,6,7,8,9,9,9,12,13,14,16,17,18,19,20,21};
// ancestor path (root..j) per joint, -1 padded; max depth 9
__constant__ int d_path[NJNT][9] = {
  {0,-1,-1,-1,-1,-1,-1,-1,-1},
  {0,1,-1,-1,-1,-1,-1,-1,-1},
  {0,2,-1,-1,-1,-1,-1,-1,-1},
  {0,3,-1,-1,-1,-1,-1,-1,-1},
  {0,1,4,-1,-1,-1,-1,-1,-1},
  {0,2,5,-1,-1,-1,-1,-1,-1},
  {0,3,6,-1,-1,-1,-1,-1,-1},
  {0,1,4,7,-1,-1,-1,-1,-1},
  {0,2,5,8,-1,-1,-1,-1,-1},
  {0,3,6,9,-1,-1,-1,-1,-1},
  {0,1,4,7,10,-1,-1,-1,-1},
  {0,2,5,8,11,-1,-1,-1,-1},
  {0,3,6,9,12,-1,-1,-1,-1},
  {0,3,6,9,13,-1,-1,-1,-1},
  {0,3,6,9,14,-1,-1,-1,-1},
  {0,3,6,9,12,15,-1,-1,-1},
  {0,3,6,9,13,16,-1,-1,-1},
  {0,3,6,9,14,17,-1,-1,-1},
  {0,3,6,9,13,16,18,-1,-1},
  {0,3,6,9,14,17,19,-1,-1},
  {0,3,6,9,13,16,18,20,-1},
  {0,3,6,9,14,17,19,21,-1},
  {0,3,6,9,13,16,18,20,22},
  {0,3,6,9,14,17,19,21,23}};

__device__ inline short f2bf(float f) {
  union { float f; unsigned u; } x; x.f = f;
  unsigned r = (x.u + 0x7fffu + ((x.u >> 16) & 1u)) >> 16;
  return (short)r;
}

// ============ kA: transpose || SJ || rodrigues (all parallel-short roles) ============
__global__ void __launch_bounds__(256) kA(const float* __restrict__ jr,
                                          const float* __restrict__ lbs,
                                          const float* __restrict__ Jreg,
                                          const float* __restrict__ sdirs,
                                          const float* __restrict__ vtmpl,
                                          const float* __restrict__ theta,
                                          const float* __restrict__ beta,
                                          float* __restrict__ jrT, float* __restrict__ wT,
                                          float* __restrict__ SJ, float* __restrict__ Rs,
                                          float* __restrict__ pfc) {
  __shared__ float red[4][3];
  int bx = blockIdx.x, tid = threadIdx.x;
  if (bx < TRB) {
    int idx = bx * 256 + tid;
    if (idx < NV * NJO)  { int v = idx / NJO,  j = idx - v * NJO;  jrT[j * NV + v] = jr[idx]; }
    if (idx < NV * NJNT) { int v = idx / NJNT, k = idx - v * NJNT; wT[k * NV + v]  = lbs[idx]; }
  } else if (bx < TRB + SJB) {
    int s = bx - TRB;
    int j = s % NJNT, k = s / NJNT;
    const float* src = (k < NBETA) ? (sdirs + (size_t)k * N3) : vtmpl;
    float a0 = 0.f, a1 = 0.f, a2 = 0.f;
    for (int v = tid; v < NV; v += 256) {
      float w = Jreg[v * NJNT + j];
      a0 += w * src[v * 3 + 0];
      a1 += w * src[v * 3 + 1];
      a2 += w * src[v * 3 + 2];
    }
    int lane = tid & 63, wid = tid >> 6;
#pragma unroll
    for (int s2 = 1; s2 < 64; s2 <<= 1) {
      a0 += __shfl_xor(a0, s2); a1 += __shfl_xor(a1, s2); a2 += __shfl_xor(a2, s2);
    }
    if (lane == 0) { red[wid][0] = a0; red[wid][1] = a1; red[wid][2] = a2; }
    __syncthreads();
    if (tid == 0) {
      float* o = SJ + (k * NJNT + j) * 3;
      o[0] = red[0][0] + red[1][0] + red[2][0] + red[3][0];
      o[1] = red[0][1] + red[1][1] + red[2][1] + red[3][1];
      o[2] = red[0][2] + red[1][2] + red[2][2] + red[3][2];
    }
  } else {
    int b = (bx - TRB - SJB) * 256 + tid;
    if (b >= NBATCH) return;
    for (int j = 0; j < NJNT; ++j) {
      float a0 = theta[b * 72 + j * 3 + 0];
      float a1 = theta[b * 72 + j * 3 + 1];
      float a2 = theta[b * 72 + j * 3 + 2];
      float e0 = a0 + 1e-8f, e1 = a1 + 1e-8f, e2 = a2 + 1e-8f;
      float ang = sqrtf(e0 * e0 + e1 * e1 + e2 * e2);
      float inv = 1.0f / ang;
      float h = 0.5f * ang;
      float w = cosf(h), s = sinf(h);
      float x = a0 * inv * s, y = a1 * inv * s, z = a2 * inv * s;
      float R[9];
      R[0] = w*w + x*x - y*y - z*z; R[1] = 2.f*(x*y - w*z); R[2] = 2.f*(x*z + w*y);
      R[3] = 2.f*(x*y + w*z); R[4] = w*w - x*x + y*y - z*z; R[5] = 2.f*(y*z - w*x);
      R[6] = 2.f*(x*z - w*y); R[7] = 2.f*(y*z + w*x); R[8] = w*w - x*x - y*y + z*z;
#pragma unroll
      for (int r = 0; r < 9; ++r) Rs[b * 216 + j * 9 + r] = R[r];
      if (j >= 1) {
#pragma unroll
        for (int r = 0; r < 9; ++r)
          pfc[b * CSTR + (j - 1) * 9 + r] = R[r] - ((r % 4 == 0) ? 1.0f : 0.0f);
      }
    }
#pragma unroll
    for (int i = 0; i < NBETA; ++i) pfc[b * CSTR + NPF + i] = beta[b * NBETA + i];
    pfc[b * CSTR + NPF + NBETA] = 1.0f;
  }
}

// ============ k_Jsmall: J[b][r] = SJ[10][r] + sum_k beta[b,k]*SJ[k][r] ============
__global__ void k_Jsmall(const float* __restrict__ beta, const float* __restrict__ SJ,
                         float* __restrict__ J) {
  int idx = blockIdx.x * 256 + threadIdx.x;
  if (idx >= NBATCH * 72) return;
  int b = idx / 72, r = idx - b * 72;
  float acc = SJ[NBETA * 72 + r];
  const float* bb = beta + b * NBETA;
#pragma unroll
  for (int k = 0; k < NBETA; ++k) acc += bb[k] * SJ[k * 72 + r];
  J[idx] = acc;
}

// ============ k_chainP: parallel path-product chain; thread = (b, j) ============
// World A_j = M_{path[0]} . M_{path[1]} ... M_j, all in registers (identical
// left-to-right order as the sequential recursion -> bit-identical).
__global__ void __launch_bounds__(256) k_chainP(const float* __restrict__ Rs,
                                                const float* __restrict__ Jin,
                                                float* __restrict__ A) {
  int idx = blockIdx.x * 256 + threadIdx.x;
  if (idx >= NBATCH * NJNT) return;
  int b = idx / NJNT, j = idx - b * NJNT;
  const float* Rb = Rs + b * 216;
  const float* Jb = Jin + b * 72;
  float T[12];
  // root: M0 = [R0 | J0]
#pragma unroll
  for (int r = 0; r < 3; ++r) {
    T[r * 4 + 0] = Rb[r * 3 + 0];
    T[r * 4 + 1] = Rb[r * 3 + 1];
    T[r * 4 + 2] = Rb[r * 3 + 2];
    T[r * 4 + 3] = Jb[r];
  }
  for (int d = 1; d < 9; ++d) {
    int i = d_path[j][d];
    if (i < 0) break;
    int p = d_par[i];
    const float* R = Rb + i * 9;
    float R0 = R[0], R1 = R[1], R2 = R[2], R3 = R[3], R4 = R[4];
    float R5 = R[5], R6 = R[6], R7 = R[7], R8 = R[8];
    float t0 = Jb[i * 3 + 0] - Jb[p * 3 + 0];
    float t1 = Jb[i * 3 + 1] - Jb[p * 3 + 1];
    float t2 = Jb[i * 3 + 2] - Jb[p * 3 + 2];
#pragma unroll
    for (int r = 0; r < 3; ++r) {
      float a0 = T[r * 4 + 0], a1 = T[r * 4 + 1], a2 = T[r * 4 + 2];
      T[r * 4 + 0] = a0 * R0 + a1 * R3 + a2 * R6;
      T[r * 4 + 1] = a0 * R1 + a1 * R4 + a2 * R7;
      T[r * 4 + 2] = a0 * R2 + a1 * R5 + a2 * R8;
      T[r * 4 + 3] = a0 * t0 + a1 * t1 + a2 * t2 + T[r * 4 + 3];
    }
  }
  float jx = Jb[j * 3 + 0], jy = Jb[j * 3 + 1], jz = Jb[j * 3 + 2];
  float* Ab = A + b * 288 + j * 12;
#pragma unroll
  for (int r = 0; r < 3; ++r) {
    float o0 = T[r * 4 + 0], o1 = T[r * 4 + 1], o2 = T[r * 4 + 2];
    Ab[r * 4 + 0] = o0;
    Ab[r * 4 + 1] = o1;
    Ab[r * 4 + 2] = o2;
    Ab[r * 4 + 3] = T[r * 4 + 3] - (o0 * jx + o1 * jy + o2 * jz);
  }
}

// ============ kPrep: Cm || Pm (coalesced) || pad-zero — uniform streaming only ========
__global__ void __launch_bounds__(256) kPrep(const float* __restrict__ jrT,
                                             const float* __restrict__ wT,
                                             const float* __restrict__ pdirs,
                                             const float* __restrict__ sdirs,
                                             const float* __restrict__ vtmpl,
                                             short* __restrict__ Cb, short* __restrict__ Pb) {
  __shared__ float buf[768];
  int bx = blockIdx.x, tid = threadIdx.x;
  if (bx < CMB) {
    int jk = bx;
    bool real = (jk < NJK);
    int j = jk / NJNT, k = jk - j * NJNT;
    for (int g = tid; g < KPAD; g += 256) {
      float val = (real && g < NV) ? jrT[j * NV + g] * wT[k * NV + g] : 0.f;
      Cb[(size_t)jk * KPAD + g] = f2bf(val);
    }
  } else if (bx < CMB + PMB) {
    int s = bx - CMB;
    const float* src; int base;
    if (s < 207)      { src = pdirs + (size_t)s * N3;         base = 3 * s; }
    else if (s < 217) { src = sdirs + (size_t)(s - 207) * N3; base = 621 + 3 * (s - 207); }
    else              { src = vtmpl;                           base = 651; }
    for (int g = 0; g < 27; ++g) {
      int f0 = g * 768;
#pragma unroll
      for (int c = 0; c < 3; ++c) {
        int fi = f0 + c * 256 + tid;
        buf[c * 256 + tid] = (fi < N3) ? src[fi] : 0.f;
      }
      __syncthreads();
      int v0 = g * 256;
#pragma unroll
      for (int q = 0; q < 3; ++q)
        Pb[(size_t)(base + q) * KPAD + v0 + tid] = f2bf(buf[tid * 3 + q]);
      __syncthreads();
    }
    if (s == 217) {
      for (int i = tid; i < KPAD; i += 256)
        Pb[(size_t)654 * KPAD + i] = (i < NV) ? f2bf(1.0f) : (short)0;
    }
  } else {
    int row = 655 + (bx - CMB - PMB);
    for (int g = tid; g < KPAD; g += 256)
      Pb[(size_t)row * KPAD + g] = (short)0;
  }
}

// ============ MFMA GEMM: Dpart[z][m][n] = sum_k P[m][k]*C[n][k] ============
__global__ void __launch_bounds__(256) k_gemm(const short* __restrict__ Pb,
                                              const short* __restrict__ Cb,
                                              float* __restrict__ Dpart) {
  int m0 = blockIdx.x * 64;
  int n0 = blockIdx.y * 64;
  int kb0 = blockIdx.z * KCH;
  __shared__ __align__(16) short As[64 * 64];
  __shared__ __align__(16) short Bs[64 * 64];
  int t = threadIdx.x;
  int wid = t >> 6, lane = t & 63;
  int frow = wid * 16 + (lane & 15);
  int fgrp = lane >> 4;
  fx4 acc[4];
#pragma unroll
  for (int j = 0; j < 4; ++j)
#pragma unroll
    for (int r = 0; r < 4; ++r) acc[j][r] = 0.f;

  int c0 = t, c1 = t + 256;
  int row0 = c0 >> 3, g0 = c0 & 7, sw0 = g0 ^ (row0 & 7);
  int row1 = c1 >> 3, g1 = c1 & 7, sw1 = g1 ^ (row1 & 7);

  for (int kk = 0; kk < KCH / 64; ++kk) {
    int kb = kb0 + kk * 64;
    *(bfx8*)(As + row0 * 64 + sw0 * 8) = *(const bfx8*)(Pb + (size_t)(m0 + row0) * KPAD + kb + g0 * 8);
    *(bfx8*)(As + row1 * 64 + sw1 * 8) = *(const bfx8*)(Pb + (size_t)(m0 + row1) * KPAD + kb + g1 * 8);
    *(bfx8*)(Bs + row0 * 64 + sw0 * 8) = *(const bfx8*)(Cb + (size_t)(n0 + row0) * KPAD + kb + g0 * 8);
    *(bfx8*)(Bs + row1 * 64 + sw1 * 8) = *(const bfx8*)(Cb + (size_t)(n0 + row1) * KPAD + kb + g1 * 8);
    __syncthreads();
#pragma unroll
    for (int ks = 0; ks < 2; ++ks) {
      int ga = ks * 4 + fgrp;
      bfx8 a = *(const bfx8*)(As + frow * 64 + (ga ^ (frow & 7)) * 8);
#pragma unroll
      for (int j = 0; j < 4; ++j) {
        int bcol = j * 16 + (lane & 15);
        bfx8 b = *(const bfx8*)(Bs + bcol * 64 + (ga ^ (bcol & 7)) * 8);
        acc[j] = __builtin_amdgcn_mfma_f32_16x16x32_bf16(a, b, acc[j], 0, 0, 0);
      }
    }
    __syncthreads();
  }
  float* dst = Dpart + (size_t)blockIdx.z * PROWSP * NJKP
             + (size_t)(m0 + wid * 16 + (lane >> 4) * 4) * NJKP + n0 + (lane & 15);
#pragma unroll
  for (int j = 0; j < 4; ++j)
#pragma unroll
    for (int r = 0; r < 4; ++r)
      dst[(size_t)r * NJKP + j * 16] = acc[j][r];
}

// ============ reduce K-split partials (float4) ============
__global__ void k_redD(const float* __restrict__ Dpart, float* __restrict__ D) {
  int i = blockIdx.x * 256 + threadIdx.x;
  if (i >= PROWSP * NJKP / 4) return;
  const float4* dp = (const float4*)Dpart;
  float4 s = dp[i];
#pragma unroll
  for (int z = 1; z < KSPLIT; ++z) {
    float4 v = dp[(size_t)z * (PROWSP * NJKP / 4) + i];
    s.x += v.x; s.y += v.y; s.z += v.z; s.w += v.w;
  }
  ((float4*)D)[i] = s;
}

// ============ k_S3: S[b][jk][q] = sum_r pfc[b][r]*D[3r+q][jk] ============
__global__ void __launch_bounds__(256) k_S3(const float* __restrict__ D,
                                            const float* __restrict__ pfc,
                                            float* __restrict__ S) {
  int n0 = blockIdx.x * 64;
  int b0 = blockIdx.y * 8;
  int tid = threadIdx.x;
  __shared__ float cf[8][NCOEF + 2];
  for (int i = tid; i < 8 * NCOEF; i += 256) {
    int b = i / NCOEF, r = i - b * NCOEF;
    cf[b][r] = pfc[(b0 + b) * CSTR + r];
  }
  __syncthreads();
  int jk = n0 + (tid & 63);
  int bg = (tid >> 6) * 2;
  float a00=0.f,a01=0.f,a02=0.f,a10=0.f,a11=0.f,a12=0.f;
  const float* Dp = D + jk;
#pragma unroll 4
  for (int r = 0; r < NCOEF; ++r) {
    float d0 = Dp[(size_t)(3 * r + 0) * NJKP];
    float d1 = Dp[(size_t)(3 * r + 1) * NJKP];
    float d2 = Dp[(size_t)(3 * r + 2) * NJKP];
    float c0 = cf[bg + 0][r];
    float c1 = cf[bg + 1][r];
    a00 += c0 * d0; a01 += c0 * d1; a02 += c0 * d2;
    a10 += c1 * d0; a11 += c1 * d1; a12 += c1 * d2;
  }
  if (jk < NJK) {
    float* o0 = S + ((size_t)(b0 + bg + 0) * NJK + jk) * 3;
    float* o1 = S + ((size_t)(b0 + bg + 1) * NJK + jk) * 3;
    o0[0] = a00; o0[1] = a01; o0[2] = a02;
    o1[0] = a10; o1[1] = a11; o1[2] = a12;
  }
}

// ============ final: joints[b,j,c] = sum_k A[b,k,c,:].[S, c0] ============
__global__ void k_final(const float* __restrict__ S, const float* __restrict__ D,
                        const float* __restrict__ A, float* __restrict__ out) {
  int idx = blockIdx.x * 256 + threadIdx.x;
  if (idx >= NBATCH * NJO * 3) return;
  int b = idx / 57, r = idx - b * 57;
  int j = r / 3, c = r - j * 3;
  const float* c0 = D + (size_t)654 * NJKP + j * NJNT;
  float acc = 0.f;
#pragma unroll
  for (int k = 0; k < NJNT; ++k) {
    const float* Ar = A + b * 288 + k * 12 + c * 4;
    const float* Sr = S + ((size_t)b * NJK + j * NJNT + k) * 3;
    acc += Ar[0] * Sr[0] + Ar[1] * Sr[1] + Ar[2] * Sr[2] + Ar[3] * c0[k];
  }
  out[idx] = acc;
}

extern "C" void kernel_launch(void* const* d_in, const int* in_sizes, int n_in,
                              void* d_out, int out_size, void* d_ws, size_t ws_size,
                              hipStream_t stream) {
  const float* beta  = (const float*)d_in[0];
  const float* theta = (const float*)d_in[1];
  const float* vtmpl = (const float*)d_in[2];
  const float* sdirs = (const float*)d_in[3];
  const float* Jreg  = (const float*)d_in[4];
  const float* pdirs = (const float*)d_in[5];
  const float* lbs   = (const float*)d_in[6];
  const float* jreg2 = (const float*)d_in[7];
  float* out = (float*)d_out;

  float* ws    = (float*)d_ws;
  short* Cb    = (short*)ws;                              // 512*6912 bf16
  short* Pb    = Cb + (size_t)NJKP * KPAD;                // 704*6912 bf16
  float* Dpart = (float*)(Pb + (size_t)PROWSP * KPAD);    // 12*704*512 f32
  float* D     = Dpart + (size_t)KSPLIT * PROWSP * NJKP;  // 704*512
  float* S     = D     + (size_t)PROWSP * NJKP;           // 512*456*3
  float* pfc   = S     + (size_t)NBATCH * NJK * 3;        // 512*224
  float* Rs    = pfc   + (size_t)NBATCH * CSTR;           // 512*216
  float* Jout  = Rs    + (size_t)NBATCH * 216;            // 512*72
  float* A     = Jout  + (size_t)NBATCH * 72;             // 512*288
  float* jrT   = A     + (size_t)NBATCH * 288;            // 19*6890
  float* wT    = jrT   + (size_t)NJO * NV;                // 24*6890
  float* SJ    = wT    + (size_t)NJNT * NV;               // 11*72

  kA<<<dim3(TRB + SJB + 2), 256, 0, stream>>>(jreg2, lbs, Jreg, sdirs, vtmpl, theta, beta,
                                              jrT, wT, SJ, Rs, pfc);
  k_Jsmall<<<dim3((NBATCH * 72 + 255) / 256), 256, 0, stream>>>(beta, SJ, Jout);
  k_chainP<<<dim3((NBATCH * NJNT + 255) / 256), 256, 0, stream>>>(Rs, Jout, A);
  kPrep<<<dim3(CMB + PMB + PZB), 256, 0, stream>>>(jrT, wT, pdirs, sdirs, vtmpl, Cb, Pb);
  k_gemm<<<dim3(PROWSP / 64, NJKP / 64, KSPLIT), 256, 0, stream>>>(Pb, Cb, Dpart);
  k_redD<<<dim3(PROWSP * NJKP / 4 / 256), 256, 0, stream>>>(Dpart, D);
  k_S3<<<dim3(NJKP / 64, NBATCH / 8), 256, 0, stream>>>(D, pfc, S);
  k_final<<<dim3((NBATCH * NJO * 3 + 255) / 256), 256, 0, stream>>>(S, D, A, out);
}